// Round 1
// baseline (2873.722 us; speedup 1.0000x reference)
//
#include <hip/hip_runtime.h>
#include <math.h>

#define NB   4
#define SLQ  2048
#define SLK  2048
#define DIM  512
#define NH   8
#define HD   64          // head dim
#define NROWS (NB * SLQ) // 8192

// ---------------------------------------------------------------------------
// Generic tiled fp32 GEMM: C[N,512] = A[N,512] @ W[512,512] + bias
// Optional fused epilogue (RELU_RES): C = A + relu(A@W + bias)
// Tile 64x64, 256 threads, 4x4 micro-tile per thread, BK=16.
// ---------------------------------------------------------------------------
template <bool RELU_RES>
__global__ __launch_bounds__(256)
void gemm_bias_kernel(const float* __restrict__ A, const float* __restrict__ W,
                      const float* __restrict__ bias, float* __restrict__ C) {
    __shared__ float As[64][17];   // +1 pad: avoids 4-way bank conflict on a-reads
    __shared__ float Ws[16][64];

    const int t   = threadIdx.x;
    const int tm  = t >> 4;        // 0..15
    const int tn  = t & 15;        // 0..15
    const int row0 = blockIdx.y << 6;
    const int col0 = blockIdx.x << 6;

    const int ra = t >> 2, ca = (t & 3) << 2;    // A-tile load coords (64x16)
    const int rw = t >> 4, cw = (t & 15) << 2;   // W-tile load coords (16x64)

    float acc[4][4] = {};

    for (int k0 = 0; k0 < DIM; k0 += 16) {
        const float4 av = *reinterpret_cast<const float4*>(
            &A[(size_t)(row0 + ra) * DIM + k0 + ca]);
        const float4 wv = *reinterpret_cast<const float4*>(
            &W[(size_t)(k0 + rw) * DIM + col0 + cw]);
        As[ra][ca + 0] = av.x; As[ra][ca + 1] = av.y;
        As[ra][ca + 2] = av.z; As[ra][ca + 3] = av.w;
        *reinterpret_cast<float4*>(&Ws[rw][cw]) = wv;
        __syncthreads();

        #pragma unroll
        for (int kk = 0; kk < 16; ++kk) {
            float a[4];
            #pragma unroll
            for (int i = 0; i < 4; ++i) a[i] = As[tm * 4 + i][kk];
            const float4 bv = *reinterpret_cast<const float4*>(&Ws[kk][tn << 2]);
            #pragma unroll
            for (int i = 0; i < 4; ++i) {
                acc[i][0] += a[i] * bv.x;
                acc[i][1] += a[i] * bv.y;
                acc[i][2] += a[i] * bv.z;
                acc[i][3] += a[i] * bv.w;
            }
        }
        __syncthreads();
    }

    const float4 bv = *reinterpret_cast<const float4*>(&bias[col0 + (tn << 2)]);
    #pragma unroll
    for (int i = 0; i < 4; ++i) {
        const int row = row0 + tm * 4 + i;
        float4 v;
        v.x = acc[i][0] + bv.x;
        v.y = acc[i][1] + bv.y;
        v.z = acc[i][2] + bv.z;
        v.w = acc[i][3] + bv.w;
        if (RELU_RES) {
            const float4 r = *reinterpret_cast<const float4*>(
                &A[(size_t)row * DIM + col0 + (tn << 2)]);
            v.x = r.x + fmaxf(v.x, 0.f);
            v.y = r.y + fmaxf(v.y, 0.f);
            v.z = r.z + fmaxf(v.z, 0.f);
            v.w = r.w + fmaxf(v.w, 0.f);
        }
        *reinterpret_cast<float4*>(&C[(size_t)row * DIM + col0 + (tn << 2)]) = v;
    }
}

// ---------------------------------------------------------------------------
// Masked flash attention, fp32.
// One 64-thread block (1 wave) per (b, h, q-tile of 64 rows).
// Thread t owns query row (q0 + t): q[64] and O-accum[64] in registers,
// K/V tiles (64x64) staged in LDS, gated online softmax for pad_mask.
// ---------------------------------------------------------------------------
__global__ __launch_bounds__(64, 1)
void attn_kernel(const float* __restrict__ Qh, const float* __restrict__ Kh,
                 const float* __restrict__ Vh, const int* __restrict__ maskp,
                 float* __restrict__ Oa) {
    const int qb = blockIdx.x;   // q tile (0..31)
    const int h  = blockIdx.y;   // head
    const int b  = blockIdx.z;   // batch
    const int t  = threadIdx.x;  // 0..63 = query row within tile

    __shared__ float Kt[64][64];
    __shared__ float Vt[64][64];
    __shared__ float mk[64];

    const size_t base_q = ((size_t)b * SLQ + (size_t)qb * 64) * DIM + (size_t)h * HD;

    float q[64];
    #pragma unroll
    for (int d4 = 0; d4 < 16; ++d4) {
        const float4 v = *reinterpret_cast<const float4*>(
            &Qh[base_q + (size_t)t * DIM + d4 * 4]);
        q[d4 * 4 + 0] = v.x; q[d4 * 4 + 1] = v.y;
        q[d4 * 4 + 2] = v.z; q[d4 * 4 + 3] = v.w;
    }

    float o[64];
    #pragma unroll
    for (int i = 0; i < 64; ++i) o[i] = 0.f;
    float m_run = -1e30f, l_run = 0.f;
    const float scale = 0.04419417382415922f;  // 1/sqrt(512)

    for (int k0 = 0; k0 < SLK; k0 += 64) {
        const size_t base_k = ((size_t)b * SLK + k0) * DIM + (size_t)h * HD;
        __syncthreads();
        // cooperative coalesced staging: lane t loads column t of each row
        for (int r = 0; r < 64; ++r) {
            Kt[r][t] = Kh[base_k + (size_t)r * DIM + t];
            Vt[r][t] = Vh[base_k + (size_t)r * DIM + t];
        }
        mk[t] = (float)maskp[b * SLK + k0 + t];
        __syncthreads();

        for (int kk = 0; kk < 64; ++kk) {
            float s = 0.f;
            #pragma unroll
            for (int d4 = 0; d4 < 16; ++d4) {
                const float4 kv = *reinterpret_cast<const float4*>(&Kt[kk][d4 * 4]);
                s += q[d4 * 4 + 0] * kv.x; s += q[d4 * 4 + 1] * kv.y;
                s += q[d4 * 4 + 2] * kv.z; s += q[d4 * 4 + 3] * kv.w;
            }
            s *= scale;
            const bool valid = (mk[kk] != 0.f);
            const float mn   = valid ? fmaxf(m_run, s) : m_run;
            const float corr = __expf(m_run - mn);          // 1 when mn==m_run
            const float p    = valid ? __expf(s - mn) : 0.f;
            l_run = l_run * corr + p;
            m_run = mn;
            #pragma unroll
            for (int d4 = 0; d4 < 16; ++d4) {
                const float4 vv = *reinterpret_cast<const float4*>(&Vt[kk][d4 * 4]);
                o[d4 * 4 + 0] = o[d4 * 4 + 0] * corr + p * vv.x;
                o[d4 * 4 + 1] = o[d4 * 4 + 1] * corr + p * vv.y;
                o[d4 * 4 + 2] = o[d4 * 4 + 2] * corr + p * vv.z;
                o[d4 * 4 + 3] = o[d4 * 4 + 3] * corr + p * vv.w;
            }
        }
    }

    const float inv = (l_run > 0.f) ? 1.f / l_run : 0.f;  // all-masked row -> 0
    #pragma unroll
    for (int d4 = 0; d4 < 16; ++d4) {
        float4 v;
        v.x = o[d4 * 4 + 0] * inv; v.y = o[d4 * 4 + 1] * inv;
        v.z = o[d4 * 4 + 2] * inv; v.w = o[d4 * 4 + 3] * inv;
        *reinterpret_cast<float4*>(&Oa[base_q + (size_t)t * DIM + d4 * 4]) = v;
    }
}

// ---------------------------------------------------------------------------
// LayerNorm: out = LN(X (+ Y)) * g + b.  One wave per row, 4 rows per block.
// ---------------------------------------------------------------------------
__device__ __forceinline__ float wave_sum(float v) {
    #pragma unroll
    for (int off = 32; off > 0; off >>= 1) v += __shfl_xor(v, off, 64);
    return v;
}

__global__ __launch_bounds__(256)
void ln_kernel(const float* __restrict__ X, const float* __restrict__ Y,
               const float* __restrict__ g, const float* __restrict__ bta,
               float* __restrict__ out) {
    const int w    = threadIdx.x >> 6;
    const int lane = threadIdx.x & 63;
    const int row  = blockIdx.x * 4 + w;
    const size_t base = (size_t)row * DIM + lane * 8;

    float v[8];
    *reinterpret_cast<float4*>(&v[0]) = *reinterpret_cast<const float4*>(&X[base]);
    *reinterpret_cast<float4*>(&v[4]) = *reinterpret_cast<const float4*>(&X[base + 4]);
    if (Y != nullptr) {
        const float4 y0 = *reinterpret_cast<const float4*>(&Y[base]);
        const float4 y1 = *reinterpret_cast<const float4*>(&Y[base + 4]);
        v[0] += y0.x; v[1] += y0.y; v[2] += y0.z; v[3] += y0.w;
        v[4] += y1.x; v[5] += y1.y; v[6] += y1.z; v[7] += y1.w;
    }

    float s = 0.f, ss = 0.f;
    #pragma unroll
    for (int i = 0; i < 8; ++i) { s += v[i]; ss += v[i] * v[i]; }
    s  = wave_sum(s);
    ss = wave_sum(ss);
    const float mean = s * (1.f / DIM);
    const float var  = ss * (1.f / DIM) - mean * mean;
    const float rstd = rsqrtf(var + 1e-5f);

    const float4 g0 = *reinterpret_cast<const float4*>(&g[lane * 8]);
    const float4 g1 = *reinterpret_cast<const float4*>(&g[lane * 8 + 4]);
    const float4 b0 = *reinterpret_cast<const float4*>(&bta[lane * 8]);
    const float4 b1 = *reinterpret_cast<const float4*>(&bta[lane * 8 + 4]);
    float gg[8] = {g0.x, g0.y, g0.z, g0.w, g1.x, g1.y, g1.z, g1.w};
    float bb[8] = {b0.x, b0.y, b0.z, b0.w, b1.x, b1.y, b1.z, b1.w};

    float4 o0, o1;
    o0.x = (v[0] - mean) * rstd * gg[0] + bb[0];
    o0.y = (v[1] - mean) * rstd * gg[1] + bb[1];
    o0.z = (v[2] - mean) * rstd * gg[2] + bb[2];
    o0.w = (v[3] - mean) * rstd * gg[3] + bb[3];
    o1.x = (v[4] - mean) * rstd * gg[4] + bb[4];
    o1.y = (v[5] - mean) * rstd * gg[5] + bb[5];
    o1.z = (v[6] - mean) * rstd * gg[6] + bb[6];
    o1.w = (v[7] - mean) * rstd * gg[7] + bb[7];
    *reinterpret_cast<float4*>(&out[base])     = o0;
    *reinterpret_cast<float4*>(&out[base + 4]) = o1;
}

// ---------------------------------------------------------------------------
extern "C" void kernel_launch(void* const* d_in, const int* in_sizes, int n_in,
                              void* d_out, int out_size, void* d_ws, size_t ws_size,
                              hipStream_t stream) {
    const float* Q     = (const float*)d_in[0];
    const float* K     = (const float*)d_in[1];
    const int*   maskp = (const int*)  d_in[2];
    const float* Wq    = (const float*)d_in[3];
    const float* bq    = (const float*)d_in[4];
    const float* Wk    = (const float*)d_in[5];
    const float* bk    = (const float*)d_in[6];
    const float* Wv    = (const float*)d_in[7];
    const float* bv    = (const float*)d_in[8];
    const float* Wo    = (const float*)d_in[9];
    const float* bo    = (const float*)d_in[10];
    const float* g0    = (const float*)d_in[11];
    const float* b0    = (const float*)d_in[12];
    const float* g1    = (const float*)d_in[13];
    const float* b1    = (const float*)d_in[14];

    float* out = (float*)d_out;
    float* wsf = (float*)d_ws;
    const size_t NELT = (size_t)NROWS * DIM;  // 4,194,304 floats (16 MB)
    float* Qh = wsf;             // projection Q
    float* Kh = wsf + NELT;      // projection K  (later reused as H1)
    float* Vh = wsf + 2 * NELT;  // projection V
    float* Oa = out;             // attention out staged in d_out
    float* H1 = Kh;              // after LN1 (Kh dead by then)
    float* R2 = Qh;              // FFN residual out (Qh dead by then)

    const dim3 gGemm(DIM / 64, NROWS / 64);   // (8, 128)
    gemm_bias_kernel<false><<<gGemm, 256, 0, stream>>>(Q, Wq, bq, Qh);
    gemm_bias_kernel<false><<<gGemm, 256, 0, stream>>>(K, Wk, bk, Kh);
    gemm_bias_kernel<false><<<gGemm, 256, 0, stream>>>(K, Wv, bv, Vh);

    attn_kernel<<<dim3(SLQ / 64, NH, NB), 64, 0, stream>>>(Qh, Kh, Vh, maskp, Oa);

    ln_kernel<<<NROWS / 4, 256, 0, stream>>>(Oa, Q, g0, b0, H1);

    gemm_bias_kernel<true><<<gGemm, 256, 0, stream>>>(H1, Wo, bo, R2);

    ln_kernel<<<NROWS / 4, 256, 0, stream>>>(R2, nullptr, g1, b1, out);
}

// Round 2
// 430.942 us; speedup vs baseline: 6.6685x; 6.6685x over previous
//
#include <hip/hip_runtime.h>
#include <math.h>

#define NB   4
#define SLQ  2048
#define SLK  2048
#define DIM  512
#define NH   8
#define HD   64          // head dim
#define NROWS (NB * SLQ) // 8192

typedef __attribute__((ext_vector_type(8))) __bf16 bf16x8;
typedef __attribute__((ext_vector_type(4))) __bf16 bf16x4;
typedef __attribute__((ext_vector_type(4))) float  f32x4;

// ---------------------------------------------------------------------------
// Tiled fp32 GEMM: C[N,512] = A[N,512] @ W[512,512] + bias
// OUT_BF16: store bf16. RELU_RES (fp32 out only): C = A + relu(A@W + bias)
// ---------------------------------------------------------------------------
template <bool OUT_BF16, bool RELU_RES>
__global__ __launch_bounds__(256)
void gemm_bias_kernel(const float* __restrict__ A, const float* __restrict__ W,
                      const float* __restrict__ bias, void* __restrict__ Cv) {
    __shared__ float As[64][17];
    __shared__ float Ws[16][64];

    const int t   = threadIdx.x;
    const int tm  = t >> 4;
    const int tn  = t & 15;
    const int row0 = blockIdx.y << 6;
    const int col0 = blockIdx.x << 6;

    const int ra = t >> 2, ca = (t & 3) << 2;
    const int rw = t >> 4, cw = (t & 15) << 2;

    float acc[4][4] = {};

    for (int k0 = 0; k0 < DIM; k0 += 16) {
        const float4 av = *reinterpret_cast<const float4*>(
            &A[(size_t)(row0 + ra) * DIM + k0 + ca]);
        const float4 wv = *reinterpret_cast<const float4*>(
            &W[(size_t)(k0 + rw) * DIM + col0 + cw]);
        As[ra][ca + 0] = av.x; As[ra][ca + 1] = av.y;
        As[ra][ca + 2] = av.z; As[ra][ca + 3] = av.w;
        *reinterpret_cast<float4*>(&Ws[rw][cw]) = wv;
        __syncthreads();

        #pragma unroll
        for (int kk = 0; kk < 16; ++kk) {
            float a[4];
            #pragma unroll
            for (int i = 0; i < 4; ++i) a[i] = As[tm * 4 + i][kk];
            const float4 bv = *reinterpret_cast<const float4*>(&Ws[kk][tn << 2]);
            #pragma unroll
            for (int i = 0; i < 4; ++i) {
                acc[i][0] += a[i] * bv.x;
                acc[i][1] += a[i] * bv.y;
                acc[i][2] += a[i] * bv.z;
                acc[i][3] += a[i] * bv.w;
            }
        }
        __syncthreads();
    }

    const float4 bv = *reinterpret_cast<const float4*>(&bias[col0 + (tn << 2)]);
    #pragma unroll
    for (int i = 0; i < 4; ++i) {
        const int row = row0 + tm * 4 + i;
        float vx = acc[i][0] + bv.x;
        float vy = acc[i][1] + bv.y;
        float vz = acc[i][2] + bv.z;
        float vw = acc[i][3] + bv.w;
        if constexpr (OUT_BF16) {
            __bf16* C = (__bf16*)Cv;
            bf16x4 hv;
            hv[0] = (__bf16)vx; hv[1] = (__bf16)vy;
            hv[2] = (__bf16)vz; hv[3] = (__bf16)vw;
            *reinterpret_cast<bf16x4*>(&C[(size_t)row * DIM + col0 + (tn << 2)]) = hv;
        } else {
            float* C = (float*)Cv;
            float4 v;
            if constexpr (RELU_RES) {
                const float4 r = *reinterpret_cast<const float4*>(
                    &A[(size_t)row * DIM + col0 + (tn << 2)]);
                v.x = r.x + fmaxf(vx, 0.f);
                v.y = r.y + fmaxf(vy, 0.f);
                v.z = r.z + fmaxf(vz, 0.f);
                v.w = r.w + fmaxf(vw, 0.f);
            } else {
                v.x = vx; v.y = vy; v.z = vz; v.w = vw;
            }
            *reinterpret_cast<float4*>(&C[(size_t)row * DIM + col0 + (tn << 2)]) = v;
        }
    }
}

// ---------------------------------------------------------------------------
// bf16 MFMA flash attention.
// Block = 256 threads (4 waves), 64 q-rows per block (16 per wave).
// Swapped QK^T: S^T[key][q] = mfma(A=K, B=Q) -> K,Q frags loaded directly
// from global (row-major, 8 consecutive d per lane). Softmax per lane
// (lane owns q-col = lane&15), P via per-wave LDS to A-layout, V staged
// transposed in LDS for the B-fragment of O = mfma(P, V).
// ---------------------------------------------------------------------------
__global__ __launch_bounds__(256)
void attn_mfma_kernel(const __bf16* __restrict__ Qh, const __bf16* __restrict__ Kh,
                      const __bf16* __restrict__ Vh, const int* __restrict__ maskp,
                      float* __restrict__ Oa) {
    const int qb  = blockIdx.x;   // q tile (64 rows)
    const int h   = blockIdx.y;
    const int b   = blockIdx.z;
    const int tid = threadIdx.x;
    const int w   = tid >> 6;     // wave 0..3
    const int l   = tid & 63;
    const int lg  = l >> 4;       // lane group 0..3
    const int lc  = l & 15;       // lane col 0..15

    __shared__ __bf16 Vt[64][72];      // V transposed [d][key], padded
    __shared__ __bf16 Pl[4][16][72];   // per-wave P [q][key], padded
    __shared__ float  mks[64];

    const int q0 = qb * 64 + w * 16;   // wave's first q row
    const __bf16* qptr = Qh + (size_t)(b * SLQ + q0 + lc) * DIM + h * HD + lg * 8;
    const bf16x8 qf0 = *reinterpret_cast<const bf16x8*>(qptr);
    const bf16x8 qf1 = *reinterpret_cast<const bf16x8*>(qptr + 32);

    f32x4 oacc[4];
    #pragma unroll
    for (int i = 0; i < 4; ++i) oacc[i] = f32x4{0.f, 0.f, 0.f, 0.f};
    float m_run = -1e30f, l_run = 0.f;
    const float scale = 0.04419417382415922f;  // 1/sqrt(512)

    for (int k0 = 0; k0 < SLK; k0 += 64) {
        __syncthreads();   // previous tile fully consumed
        {
            const int key = tid & 63, dc = tid >> 6;
            const __bf16* src = Vh + (size_t)(b * SLK + k0 + key) * DIM + h * HD + dc * 16;
            const bf16x8 v0 = *reinterpret_cast<const bf16x8*>(src);
            const bf16x8 v1 = *reinterpret_cast<const bf16x8*>(src + 8);
            #pragma unroll
            for (int j = 0; j < 8; ++j) {
                Vt[dc * 16 + j][key]     = v0[j];
                Vt[dc * 16 + 8 + j][key] = v1[j];
            }
            if (tid < 64) mks[tid] = (float)maskp[b * SLK + k0 + tid];
        }
        __syncthreads();

        // ---- S^T = K . Q^T  (C: col = q = lc, row = key = lg*4+r) ----
        f32x4 sacc[4];
        #pragma unroll
        for (int kb = 0; kb < 4; ++kb) {
            sacc[kb] = f32x4{0.f, 0.f, 0.f, 0.f};
            const __bf16* kptr = Kh + (size_t)(b * SLK + k0 + kb * 16 + lc) * DIM + h * HD + lg * 8;
            const bf16x8 kf0 = *reinterpret_cast<const bf16x8*>(kptr);
            const bf16x8 kf1 = *reinterpret_cast<const bf16x8*>(kptr + 32);
            sacc[kb] = __builtin_amdgcn_mfma_f32_16x16x32_bf16(kf0, qf0, sacc[kb], 0, 0, 0);
            sacc[kb] = __builtin_amdgcn_mfma_f32_16x16x32_bf16(kf1, qf1, sacc[kb], 0, 0, 0);
        }

        // ---- online softmax for q = lc ----
        float sef[4][4];
        float mloc = -2e30f;
        #pragma unroll
        for (int kb = 0; kb < 4; ++kb) {
            const f32x4 mv = *reinterpret_cast<const f32x4*>(&mks[kb * 16 + lg * 4]);
            #pragma unroll
            for (int r = 0; r < 4; ++r) {
                const float s = sacc[kb][r] * scale;
                sef[kb][r] = (mv[r] != 0.f) ? s : -2e30f;  // masked sentinel
                mloc = fmaxf(mloc, sef[kb][r]);
            }
        }
        mloc = fmaxf(mloc, __shfl_xor(mloc, 16, 64));
        mloc = fmaxf(mloc, __shfl_xor(mloc, 32, 64));
        const float m_new = fmaxf(m_run, mloc);
        const float corr  = __expf(m_run - m_new);
        float lloc = 0.f;
        #pragma unroll
        for (int kb = 0; kb < 4; ++kb) {
            bf16x4 pv;
            #pragma unroll
            for (int r = 0; r < 4; ++r) {
                const float p = __expf(sef[kb][r] - m_new);  // masked -> exact 0
                lloc += p;
                pv[r] = (__bf16)p;
            }
            *reinterpret_cast<bf16x4*>(&Pl[w][lc][kb * 16 + lg * 4]) = pv;
        }
        lloc += __shfl_xor(lloc, 16, 64);
        lloc += __shfl_xor(lloc, 32, 64);
        l_run = l_run * corr + lloc;
        m_run = m_new;

        // ---- rescale O (rows q = lg*4+r need corr from lane lg*4+r) ----
        float corrq[4];
        #pragma unroll
        for (int r = 0; r < 4; ++r) corrq[r] = __shfl(corr, lg * 4 + r, 64);
        #pragma unroll
        for (int db = 0; db < 4; ++db) {
            #pragma unroll
            for (int r = 0; r < 4; ++r) oacc[db][r] *= corrq[r];
        }

        // ---- O += P . V  (A = P from LDS, B = V^T from LDS) ----
        const bf16x8 pf0 = *reinterpret_cast<const bf16x8*>(&Pl[w][lc][lg * 8]);
        const bf16x8 pf1 = *reinterpret_cast<const bf16x8*>(&Pl[w][lc][32 + lg * 8]);
        #pragma unroll
        for (int db = 0; db < 4; ++db) {
            const bf16x8 vf0 = *reinterpret_cast<const bf16x8*>(&Vt[db * 16 + lc][lg * 8]);
            const bf16x8 vf1 = *reinterpret_cast<const bf16x8*>(&Vt[db * 16 + lc][32 + lg * 8]);
            oacc[db] = __builtin_amdgcn_mfma_f32_16x16x32_bf16(pf0, vf0, oacc[db], 0, 0, 0);
            oacc[db] = __builtin_amdgcn_mfma_f32_16x16x32_bf16(pf1, vf1, oacc[db], 0, 0, 0);
        }
    }

    // ---- epilogue: O row q = lg*4+r, col d = db*16+lc ----
    float invq[4];
    #pragma unroll
    for (int r = 0; r < 4; ++r) {
        const float lq = __shfl(l_run, lg * 4 + r, 64);
        invq[r] = (lq > 0.f) ? 1.f / lq : 0.f;   // all-masked row -> 0
    }
    #pragma unroll
    for (int r = 0; r < 4; ++r) {
        float* orow = Oa + (size_t)(b * SLQ + q0 + lg * 4 + r) * DIM + h * HD;
        #pragma unroll
        for (int db = 0; db < 4; ++db) orow[db * 16 + lc] = oacc[db][r] * invq[r];
    }
}

// ---------------------------------------------------------------------------
// LayerNorm: out = LN(X (+ Y)) * g + b.  One wave per row, 4 rows per block.
// ---------------------------------------------------------------------------
__device__ __forceinline__ float wave_sum(float v) {
    #pragma unroll
    for (int off = 32; off > 0; off >>= 1) v += __shfl_xor(v, off, 64);
    return v;
}

__global__ __launch_bounds__(256)
void ln_kernel(const float* __restrict__ X, const float* __restrict__ Y,
               const float* __restrict__ g, const float* __restrict__ bta,
               float* __restrict__ out) {
    const int w    = threadIdx.x >> 6;
    const int lane = threadIdx.x & 63;
    const int row  = blockIdx.x * 4 + w;
    const size_t base = (size_t)row * DIM + lane * 8;

    float v[8];
    *reinterpret_cast<float4*>(&v[0]) = *reinterpret_cast<const float4*>(&X[base]);
    *reinterpret_cast<float4*>(&v[4]) = *reinterpret_cast<const float4*>(&X[base + 4]);
    if (Y != nullptr) {
        const float4 y0 = *reinterpret_cast<const float4*>(&Y[base]);
        const float4 y1 = *reinterpret_cast<const float4*>(&Y[base + 4]);
        v[0] += y0.x; v[1] += y0.y; v[2] += y0.z; v[3] += y0.w;
        v[4] += y1.x; v[5] += y1.y; v[6] += y1.z; v[7] += y1.w;
    }

    float s = 0.f, ss = 0.f;
    #pragma unroll
    for (int i = 0; i < 8; ++i) { s += v[i]; ss += v[i] * v[i]; }
    s  = wave_sum(s);
    ss = wave_sum(ss);
    const float mean = s * (1.f / DIM);
    const float var  = ss * (1.f / DIM) - mean * mean;
    const float rstd = rsqrtf(var + 1e-5f);

    const float4 g0 = *reinterpret_cast<const float4*>(&g[lane * 8]);
    const float4 g1 = *reinterpret_cast<const float4*>(&g[lane * 8 + 4]);
    const float4 b0 = *reinterpret_cast<const float4*>(&bta[lane * 8]);
    const float4 b1 = *reinterpret_cast<const float4*>(&bta[lane * 8 + 4]);
    float gg[8] = {g0.x, g0.y, g0.z, g0.w, g1.x, g1.y, g1.z, g1.w};
    float bb[8] = {b0.x, b0.y, b0.z, b0.w, b1.x, b1.y, b1.z, b1.w};

    float4 o0, o1;
    o0.x = (v[0] - mean) * rstd * gg[0] + bb[0];
    o0.y = (v[1] - mean) * rstd * gg[1] + bb[1];
    o0.z = (v[2] - mean) * rstd * gg[2] + bb[2];
    o0.w = (v[3] - mean) * rstd * gg[3] + bb[3];
    o1.x = (v[4] - mean) * rstd * gg[4] + bb[4];
    o1.y = (v[5] - mean) * rstd * gg[5] + bb[5];
    o1.z = (v[6] - mean) * rstd * gg[6] + bb[6];
    o1.w = (v[7] - mean) * rstd * gg[7] + bb[7];
    *reinterpret_cast<float4*>(&out[base])     = o0;
    *reinterpret_cast<float4*>(&out[base + 4]) = o1;
}

// ---------------------------------------------------------------------------
extern "C" void kernel_launch(void* const* d_in, const int* in_sizes, int n_in,
                              void* d_out, int out_size, void* d_ws, size_t ws_size,
                              hipStream_t stream) {
    const float* Q     = (const float*)d_in[0];
    const float* K     = (const float*)d_in[1];
    const int*   maskp = (const int*)  d_in[2];
    const float* Wq    = (const float*)d_in[3];
    const float* bq    = (const float*)d_in[4];
    const float* Wk    = (const float*)d_in[5];
    const float* bk    = (const float*)d_in[6];
    const float* Wv    = (const float*)d_in[7];
    const float* bv    = (const float*)d_in[8];
    const float* Wo    = (const float*)d_in[9];
    const float* bo    = (const float*)d_in[10];
    const float* g0    = (const float*)d_in[11];
    const float* b0    = (const float*)d_in[12];
    const float* g1    = (const float*)d_in[13];
    const float* b1    = (const float*)d_in[14];

    float* out = (float*)d_out;
    char*  ws  = (char*)d_ws;
    const size_t NELT = (size_t)NROWS * DIM;      // 4,194,304
    __bf16* Qh = (__bf16*)(ws);                   // 8 MB
    __bf16* Kh = (__bf16*)(ws + NELT * 2);        // 8 MB
    __bf16* Vh = (__bf16*)(ws + NELT * 4);        // 8 MB
    float*  Oa = out;                             // attention out staged in d_out
    float*  H1 = (float*)(ws);                    // 16 MB, over Qh+Kh (dead)
    float*  R2 = (float*)(ws + NELT * 4);         // 16 MB, over Vh+spare (dead)

    const dim3 gGemm(DIM / 64, NROWS / 64);
    gemm_bias_kernel<true, false><<<gGemm, 256, 0, stream>>>(Q, Wq, bq, Qh);
    gemm_bias_kernel<true, false><<<gGemm, 256, 0, stream>>>(K, Wk, bk, Kh);
    gemm_bias_kernel<true, false><<<gGemm, 256, 0, stream>>>(K, Wv, bv, Vh);

    attn_mfma_kernel<<<dim3(SLQ / 64, NH, NB), 256, 0, stream>>>(Qh, Kh, Vh, maskp, Oa);

    ln_kernel<<<NROWS / 4, 256, 0, stream>>>(Oa, Q, g0, b0, H1);

    gemm_bias_kernel<false, true><<<gGemm, 256, 0, stream>>>(H1, Wo, bo, R2);

    ln_kernel<<<NROWS / 4, 256, 0, stream>>>(R2, nullptr, g1, b1, out);
}

// Round 4
// 244.104 us; speedup vs baseline: 11.7725x; 1.7654x over previous
//
#include <hip/hip_runtime.h>
#include <math.h>

#define NB   4
#define SLQ  2048
#define SLK  2048
#define DIM  512
#define NH   8
#define HD   64          // head dim
#define NROWS (NB * SLQ) // 8192

typedef __attribute__((ext_vector_type(8))) __bf16 bf16x8;
typedef __attribute__((ext_vector_type(4))) __bf16 bf16x4;
typedef __attribute__((ext_vector_type(4))) float  f32x4;

// ---------------------------------------------------------------------------
// Weight transpose + fp32->bf16: Wt[512*m + n][k] = W_m[k][n]
// m: 0=Wq 1=Wk 2=Wv 3=Wo. 32x32 tiles, 256 threads.
// ---------------------------------------------------------------------------
__global__ __launch_bounds__(256)
void transpose_w_kernel(const float* __restrict__ Wq, const float* __restrict__ Wk,
                        const float* __restrict__ Wv, const float* __restrict__ Wo,
                        __bf16* __restrict__ Wt) {
    __shared__ float Ls[32][33];
    const int m  = blockIdx.z;
    const float* W = (m == 0) ? Wq : (m == 1) ? Wk : (m == 2) ? Wv : Wo;
    const int k0 = blockIdx.y * 32, n0 = blockIdx.x * 32;
    const int t  = threadIdx.x;
    const int r  = t >> 3, c = (t & 7) * 4;

    const float4 v = *reinterpret_cast<const float4*>(&W[(size_t)(k0 + r) * DIM + n0 + c]);
    Ls[r][c + 0] = v.x; Ls[r][c + 1] = v.y; Ls[r][c + 2] = v.z; Ls[r][c + 3] = v.w;
    __syncthreads();

    const int n = t >> 3, k = (t & 7) * 4;
    bf16x4 o;
    o[0] = (__bf16)Ls[k + 0][n];
    o[1] = (__bf16)Ls[k + 1][n];
    o[2] = (__bf16)Ls[k + 2][n];
    o[3] = (__bf16)Ls[k + 3][n];
    *reinterpret_cast<bf16x4*>(&Wt[(size_t)(512 * m + n0 + n) * DIM + k0 + k]) = o;
}

// ---------------------------------------------------------------------------
// bf16 MFMA GEMM: C[M, ncols] = A[M,512](fp32) @ W(bf16, pre-transposed Bt[n][k])
// BM=128, BN=64, BK=64. 256 threads = 4 waves (2x2), wave tile 64x32.
// FFN=false: C = bf16(acc + bias), store to bf16 out (ldo = out row stride).
// FFN=true : C = A + relu(acc + bias), fp32 out (DISJOINT from A), ldo=512.
// bias pointer select: col0 < 512 -> bias_lo, else bias_hi (for fused KV).
// ---------------------------------------------------------------------------
template <bool FFN>
__global__ __launch_bounds__(256)
void gemm_mfma_kernel(const float* __restrict__ A, const __bf16* __restrict__ Bt,
                      const float* __restrict__ bias_lo, const float* __restrict__ bias_hi,
                      void* __restrict__ outv, int ldo) {
    __shared__ __bf16 As[128][72];
    __shared__ __bf16 Bs[64][72];

    const int t  = threadIdx.x;
    const int w  = t >> 6, l = t & 63, lg = l >> 4, lc = l & 15;
    const int wr = w >> 1, wc = w & 1;
    const int row0 = blockIdx.y * 128, col0 = blockIdx.x * 64;

    f32x4 acc[4][2];
    #pragma unroll
    for (int mi = 0; mi < 4; ++mi)
        #pragma unroll
        for (int nj = 0; nj < 2; ++nj) acc[mi][nj] = f32x4{0.f, 0.f, 0.f, 0.f};

    const int sr = t >> 3, sc = (t & 7) * 8;

    for (int k0 = 0; k0 < DIM; k0 += 64) {
        __syncthreads();
        // stage A (128x64 fp32 -> bf16)
        #pragma unroll
        for (int i = 0; i < 4; ++i) {
            const int r = i * 32 + sr;
            const float4 a0 = *reinterpret_cast<const float4*>(
                &A[(size_t)(row0 + r) * DIM + k0 + sc]);
            const float4 a1 = *reinterpret_cast<const float4*>(
                &A[(size_t)(row0 + r) * DIM + k0 + sc + 4]);
            bf16x8 hv;
            hv[0] = (__bf16)a0.x; hv[1] = (__bf16)a0.y;
            hv[2] = (__bf16)a0.z; hv[3] = (__bf16)a0.w;
            hv[4] = (__bf16)a1.x; hv[5] = (__bf16)a1.y;
            hv[6] = (__bf16)a1.z; hv[7] = (__bf16)a1.w;
            *reinterpret_cast<bf16x8*>(&As[r][sc]) = hv;
        }
        // stage B (64x64 bf16 copy from Bt)
        #pragma unroll
        for (int i = 0; i < 2; ++i) {
            const int n = i * 32 + sr;
            *reinterpret_cast<bf16x8*>(&Bs[n][sc]) =
                *reinterpret_cast<const bf16x8*>(&Bt[(size_t)(col0 + n) * DIM + k0 + sc]);
        }
        __syncthreads();

        #pragma unroll
        for (int ks = 0; ks < 2; ++ks) {
            bf16x8 af[4], bfv[2];
            #pragma unroll
            for (int mi = 0; mi < 4; ++mi)
                af[mi] = *reinterpret_cast<const bf16x8*>(
                    &As[wr * 64 + mi * 16 + lc][ks * 32 + lg * 8]);
            #pragma unroll
            for (int nj = 0; nj < 2; ++nj)
                bfv[nj] = *reinterpret_cast<const bf16x8*>(
                    &Bs[wc * 32 + nj * 16 + lc][ks * 32 + lg * 8]);
            #pragma unroll
            for (int mi = 0; mi < 4; ++mi)
                #pragma unroll
                for (int nj = 0; nj < 2; ++nj)
                    acc[mi][nj] = __builtin_amdgcn_mfma_f32_16x16x32_bf16(
                        af[mi], bfv[nj], acc[mi][nj], 0, 0, 0);
        }
    }

    const float* bias = (col0 < 512) ? (bias_lo + col0) : (bias_hi + col0 - 512);
    #pragma unroll
    for (int mi = 0; mi < 4; ++mi) {
        #pragma unroll
        for (int nj = 0; nj < 2; ++nj) {
            const int cl  = wc * 32 + nj * 16 + lc;
            const int col = col0 + cl;
            const float bb = bias[cl];
            #pragma unroll
            for (int r = 0; r < 4; ++r) {
                const int row = row0 + wr * 64 + mi * 16 + lg * 4 + r;
                const float vv = acc[mi][nj][r] + bb;
                if constexpr (FFN) {
                    float* out = (float*)outv;
                    out[(size_t)row * ldo + col] =
                        A[(size_t)row * DIM + col] + fmaxf(vv, 0.f);
                } else {
                    __bf16* out = (__bf16*)outv;
                    out[(size_t)row * ldo + col] = (__bf16)vv;
                }
            }
        }
    }
}

// ---------------------------------------------------------------------------
// bf16 MFMA flash attention (KV fused buffer: row stride 1024, V at +512).
// Block = 256 threads (4 waves), 64 q-rows per block (16 per wave).
// ---------------------------------------------------------------------------
__global__ __launch_bounds__(256)
void attn_mfma_kernel(const __bf16* __restrict__ Qh, const __bf16* __restrict__ KVh,
                      const int* __restrict__ maskp, float* __restrict__ Oa) {
    const int qb  = blockIdx.x;
    const int h   = blockIdx.y;
    const int b   = blockIdx.z;
    const int tid = threadIdx.x;
    const int w   = tid >> 6;
    const int l   = tid & 63;
    const int lg  = l >> 4;
    const int lc  = l & 15;

    __shared__ __bf16 Vt[64][72];
    __shared__ __bf16 Pl[4][16][72];
    __shared__ float  mks[64];

    const int q0 = qb * 64 + w * 16;
    const __bf16* qptr = Qh + (size_t)(b * SLQ + q0 + lc) * DIM + h * HD + lg * 8;
    const bf16x8 qf0 = *reinterpret_cast<const bf16x8*>(qptr);
    const bf16x8 qf1 = *reinterpret_cast<const bf16x8*>(qptr + 32);

    f32x4 oacc[4];
    #pragma unroll
    for (int i = 0; i < 4; ++i) oacc[i] = f32x4{0.f, 0.f, 0.f, 0.f};
    float m_run = -1e30f, l_run = 0.f;
    const float scale = 0.04419417382415922f;  // 1/sqrt(512)

    for (int k0 = 0; k0 < SLK; k0 += 64) {
        __syncthreads();
        {
            const int key = tid & 63, dc = tid >> 6;
            const __bf16* src = KVh + (size_t)(b * SLK + k0 + key) * 1024 + 512 + h * HD + dc * 16;
            const bf16x8 v0 = *reinterpret_cast<const bf16x8*>(src);
            const bf16x8 v1 = *reinterpret_cast<const bf16x8*>(src + 8);
            #pragma unroll
            for (int j = 0; j < 8; ++j) {
                Vt[dc * 16 + j][key]     = v0[j];
                Vt[dc * 16 + 8 + j][key] = v1[j];
            }
            if (tid < 64) mks[tid] = (float)maskp[b * SLK + k0 + tid];
        }
        __syncthreads();

        // ---- S^T = K . Q^T ----
        f32x4 sacc[4];
        #pragma unroll
        for (int kb = 0; kb < 4; ++kb) {
            sacc[kb] = f32x4{0.f, 0.f, 0.f, 0.f};
            const __bf16* kptr = KVh + (size_t)(b * SLK + k0 + kb * 16 + lc) * 1024 + h * HD + lg * 8;
            const bf16x8 kf0 = *reinterpret_cast<const bf16x8*>(kptr);
            const bf16x8 kf1 = *reinterpret_cast<const bf16x8*>(kptr + 32);
            sacc[kb] = __builtin_amdgcn_mfma_f32_16x16x32_bf16(kf0, qf0, sacc[kb], 0, 0, 0);
            sacc[kb] = __builtin_amdgcn_mfma_f32_16x16x32_bf16(kf1, qf1, sacc[kb], 0, 0, 0);
        }

        // ---- online softmax for q = lc ----
        float sef[4][4];
        float mloc = -2e30f;
        #pragma unroll
        for (int kb = 0; kb < 4; ++kb) {
            const f32x4 mv = *reinterpret_cast<const f32x4*>(&mks[kb * 16 + lg * 4]);
            #pragma unroll
            for (int r = 0; r < 4; ++r) {
                const float s = sacc[kb][r] * scale;
                sef[kb][r] = (mv[r] != 0.f) ? s : -2e30f;
                mloc = fmaxf(mloc, sef[kb][r]);
            }
        }
        mloc = fmaxf(mloc, __shfl_xor(mloc, 16, 64));
        mloc = fmaxf(mloc, __shfl_xor(mloc, 32, 64));
        const float m_new = fmaxf(m_run, mloc);
        const float corr  = __expf(m_run - m_new);
        float lloc = 0.f;
        #pragma unroll
        for (int kb = 0; kb < 4; ++kb) {
            bf16x4 pv;
            #pragma unroll
            for (int r = 0; r < 4; ++r) {
                const float p = __expf(sef[kb][r] - m_new);
                lloc += p;
                pv[r] = (__bf16)p;
            }
            *reinterpret_cast<bf16x4*>(&Pl[w][lc][kb * 16 + lg * 4]) = pv;
        }
        lloc += __shfl_xor(lloc, 16, 64);
        lloc += __shfl_xor(lloc, 32, 64);
        l_run = l_run * corr + lloc;
        m_run = m_new;

        float corrq[4];
        #pragma unroll
        for (int r = 0; r < 4; ++r) corrq[r] = __shfl(corr, lg * 4 + r, 64);
        #pragma unroll
        for (int db = 0; db < 4; ++db) {
            #pragma unroll
            for (int r = 0; r < 4; ++r) oacc[db][r] *= corrq[r];
        }

        // ---- O += P . V ----
        const bf16x8 pf0 = *reinterpret_cast<const bf16x8*>(&Pl[w][lc][lg * 8]);
        const bf16x8 pf1 = *reinterpret_cast<const bf16x8*>(&Pl[w][lc][32 + lg * 8]);
        #pragma unroll
        for (int db = 0; db < 4; ++db) {
            const bf16x8 vf0 = *reinterpret_cast<const bf16x8*>(&Vt[db * 16 + lc][lg * 8]);
            const bf16x8 vf1 = *reinterpret_cast<const bf16x8*>(&Vt[db * 16 + lc][32 + lg * 8]);
            oacc[db] = __builtin_amdgcn_mfma_f32_16x16x32_bf16(pf0, vf0, oacc[db], 0, 0, 0);
            oacc[db] = __builtin_amdgcn_mfma_f32_16x16x32_bf16(pf1, vf1, oacc[db], 0, 0, 0);
        }
    }

    float invq[4];
    #pragma unroll
    for (int r = 0; r < 4; ++r) {
        const float lq = __shfl(l_run, lg * 4 + r, 64);
        invq[r] = (lq > 0.f) ? 1.f / lq : 0.f;
    }
    #pragma unroll
    for (int r = 0; r < 4; ++r) {
        float* orow = Oa + (size_t)(b * SLQ + q0 + lg * 4 + r) * DIM + h * HD;
        #pragma unroll
        for (int db = 0; db < 4; ++db) orow[db * 16 + lc] = oacc[db][r] * invq[r];
    }
}

// ---------------------------------------------------------------------------
// LayerNorm: out = LN(X (+ Y)) * g + b.  One wave per row, 4 rows per block.
// X and out are always DISJOINT buffers (no in-place use).
// ---------------------------------------------------------------------------
__device__ __forceinline__ float wave_sum(float v) {
    #pragma unroll
    for (int off = 32; off > 0; off >>= 1) v += __shfl_xor(v, off, 64);
    return v;
}

__global__ __launch_bounds__(256)
void ln_kernel(const float* X, const float* Y,
               const float* g, const float* bta, float* out) {
    const int w    = threadIdx.x >> 6;
    const int lane = threadIdx.x & 63;
    const int row  = blockIdx.x * 4 + w;
    const size_t base = (size_t)row * DIM + lane * 8;

    float v[8];
    *reinterpret_cast<float4*>(&v[0]) = *reinterpret_cast<const float4*>(&X[base]);
    *reinterpret_cast<float4*>(&v[4]) = *reinterpret_cast<const float4*>(&X[base + 4]);
    if (Y != nullptr) {
        const float4 y0 = *reinterpret_cast<const float4*>(&Y[base]);
        const float4 y1 = *reinterpret_cast<const float4*>(&Y[base + 4]);
        v[0] += y0.x; v[1] += y0.y; v[2] += y0.z; v[3] += y0.w;
        v[4] += y1.x; v[5] += y1.y; v[6] += y1.z; v[7] += y1.w;
    }

    float s = 0.f, ss = 0.f;
    #pragma unroll
    for (int i = 0; i < 8; ++i) { s += v[i]; ss += v[i] * v[i]; }
    s  = wave_sum(s);
    ss = wave_sum(ss);
    const float mean = s * (1.f / DIM);
    const float var  = ss * (1.f / DIM) - mean * mean;
    const float rstd = rsqrtf(var + 1e-5f);

    const float4 g0 = *reinterpret_cast<const float4*>(&g[lane * 8]);
    const float4 g1 = *reinterpret_cast<const float4*>(&g[lane * 8 + 4]);
    const float4 b0 = *reinterpret_cast<const float4*>(&bta[lane * 8]);
    const float4 b1 = *reinterpret_cast<const float4*>(&bta[lane * 8 + 4]);
    float gg[8] = {g0.x, g0.y, g0.z, g0.w, g1.x, g1.y, g1.z, g1.w};
    float bb[8] = {b0.x, b0.y, b0.z, b0.w, b1.x, b1.y, b1.z, b1.w};

    float4 o0, o1;
    o0.x = (v[0] - mean) * rstd * gg[0] + bb[0];
    o0.y = (v[1] - mean) * rstd * gg[1] + bb[1];
    o0.z = (v[2] - mean) * rstd * gg[2] + bb[2];
    o0.w = (v[3] - mean) * rstd * gg[3] + bb[3];
    o1.x = (v[4] - mean) * rstd * gg[4] + bb[4];
    o1.y = (v[5] - mean) * rstd * gg[5] + bb[5];
    o1.z = (v[6] - mean) * rstd * gg[6] + bb[6];
    o1.w = (v[7] - mean) * rstd * gg[7] + bb[7];
    *reinterpret_cast<float4*>(&out[base])     = o0;
    *reinterpret_cast<float4*>(&out[base + 4]) = o1;
}

// ---------------------------------------------------------------------------
// Workspace layout (42 MB total; ws >= 48 MB proven by round-1 usage):
//   Qh  bf16 @ 0 .. 8 MB     (Qproj -> attn)
//   KVh bf16 @ 8 .. 24 MB    (KVproj -> attn)
//   Wt  bf16 @ 24 .. 26 MB   (transpose -> all GEMMs)
//   H1  f32  @ 26 .. 42 MB   (LN1 -> FFN)   [no overlap with anything live]
//   R2  f32  @ 0 .. 16 MB    (FFN -> LN2)   [over DEAD Qh + KVh first half]
// d_out: attn writes Oa, LN1 consumes it; LN2 (R2 -> d_out) overwrites last.
// No buffer is ever read before being written in the same call; no in-place.
// ---------------------------------------------------------------------------
extern "C" void kernel_launch(void* const* d_in, const int* in_sizes, int n_in,
                              void* d_out, int out_size, void* d_ws, size_t ws_size,
                              hipStream_t stream) {
    const float* Q     = (const float*)d_in[0];
    const float* K     = (const float*)d_in[1];
    const int*   maskp = (const int*)  d_in[2];
    const float* Wq    = (const float*)d_in[3];
    const float* bq    = (const float*)d_in[4];
    const float* Wk    = (const float*)d_in[5];
    const float* bk    = (const float*)d_in[6];
    const float* Wv    = (const float*)d_in[7];
    const float* bv    = (const float*)d_in[8];
    const float* Wo    = (const float*)d_in[9];
    const float* bo    = (const float*)d_in[10];
    const float* g0    = (const float*)d_in[11];
    const float* b0    = (const float*)d_in[12];
    const float* g1    = (const float*)d_in[13];
    const float* b1    = (const float*)d_in[14];

    float* out = (float*)d_out;
    char*  ws  = (char*)d_ws;
    __bf16* Qh  = (__bf16*)ws;
    __bf16* KVh = (__bf16*)(ws + (8u  << 20));
    __bf16* Wt  = (__bf16*)(ws + (24u << 20));
    float*  H1  = (float*)(ws + (26u << 20));
    float*  R2  = (float*)ws;
    float*  Oa  = out;

    transpose_w_kernel<<<dim3(16, 16, 4), 256, 0, stream>>>(Wq, Wk, Wv, Wo, Wt);

    // Q projection: N=512
    gemm_mfma_kernel<false><<<dim3(8, 64), 256, 0, stream>>>(
        Q, Wt, bq, bq, Qh, 512);
    // fused K+V projection: N=1024 (cols 0..511 = K heads, 512..1023 = V heads)
    gemm_mfma_kernel<false><<<dim3(16, 64), 256, 0, stream>>>(
        K, Wt + (size_t)512 * DIM, bk, bv, KVh, 1024);

    attn_mfma_kernel<<<dim3(SLQ / 64, NH, NB), 256, 0, stream>>>(Qh, KVh, maskp, Oa);

    ln_kernel<<<NROWS / 4, 256, 0, stream>>>(Oa, Q, g0, b0, H1);

    gemm_mfma_kernel<true><<<dim3(8, 64), 256, 0, stream>>>(
        H1, Wt + (size_t)1536 * DIM, bo, bo, R2, 512);

    ln_kernel<<<NROWS / 4, 256, 0, stream>>>(R2, nullptr, g1, b1, out);
}